// Round 8
// baseline (4862.073 us; speedup 1.0000x reference)
//
#include <hip/hip_runtime.h>
#include <hip/hip_bf16.h>
#include <hip/hip_fp16.h>
#include <stdint.h>

// Problem: T=512, B=128, INPUT=256, HIDDEN=512
//   xp = einsum('tbi,hi->tbh', x, Wx) + b      (phase 1, parallel GEMM)
//   h_{t+1} = tanh(xp_t + h_t @ Wh^T)          (phase 2, 512 sequential steps)
//   out = [h0(=0); h1..h512]  fp32, shape (513,128,512)
//
// R9 (3rd submit; R6/R7 infra failures — never measured): scan is
// LDS-PIPE-bound (R8 counters: whl reads 1536cy + h 768cy + shfl-swizzles
// ~1000cy per CU-step vs VALU 1150cy; __shfl_xor = ds_swizzle = LDS pipe,
// which is why R8's butterfly REGRESSED 818->897).
//  - ALL 8 weight rows now register-resident (256 pinned u32; pins live in
//    the unified VGPR/AGPR file, v_dot2 reads them directly — R7/R8 proven
//    no-scratch). whl LDS buffer deleted -> LDS ~2.5KB (h ping/pong only).
//  - reduce via DPP (VALU pipe): quad_perm 0xB1 (^1), 0x4E (^2),
//    row_half_mirror 0x141 (crosses quads; all quad lanes equal by then).
//    8-lane ks-groups never cross a 16-lane DPP row.
//  - keep: ONE barrier/step (h double-buffer), xp_{t+1} prefetch,
//    cndmask select, in-place xp->h overwrite in d_out.
#define T_STEPS 512
#define BATCH   128
#define NIN     256
#define HID     512

typedef _Float16 f16x2 __attribute__((ext_vector_type(2)));
typedef unsigned int u32x4 __attribute__((ext_vector_type(4)));

__device__ __forceinline__ float fdot2u(uint32_t a, uint32_t b, float c) {
#if __has_builtin(__builtin_amdgcn_fdot2)
  return __builtin_amdgcn_fdot2(__builtin_bit_cast(f16x2, a),
                                __builtin_bit_cast(f16x2, b), c, false);
#else
  __half2 ha = __builtin_bit_cast(__half2, a);
  __half2 hb = __builtin_bit_cast(__half2, b);
  return c + __half2float(ha.x) * __half2float(hb.x)
           + __half2float(ha.y) * __half2float(hb.y);
#endif
}

__device__ __forceinline__ float dot8(uint4 w, uint4 x, float a) {
  a = fdot2u(w.x, x.x, a);
  a = fdot2u(w.y, x.y, a);
  a = fdot2u(w.z, x.z, a);
  a = fdot2u(w.w, x.w, a);
  return a;
}

// v += (v shuffled by DPP ctrl) — stays on the VALU pipe (mov_dpp + add)
template <int CTRL>
__device__ __forceinline__ float dppadd(float v) {
  int x = __builtin_bit_cast(int, v);
  int y = __builtin_amdgcn_update_dpp(x, x, CTRL, 0xF, 0xF, true);
  return v + __builtin_bit_cast(float, y);
}

// ------------- phase 0: split + convert W (fp32[512][768]) to f16 -----------
__global__ void prep_w(const float* __restrict__ W,
                       __half* __restrict__ Wx, __half* __restrict__ Wh) {
  int idx = blockIdx.x * 256 + threadIdx.x;   // exactly 512*768 threads
  int h = idx / (NIN + HID);
  int c = idx - h * (NIN + HID);
  float v = W[idx];
  if (c < NIN) Wx[h * NIN + c] = __float2half(v);
  else         Wh[h * HID + (c - NIN)] = __float2half(v);
}

// ---------------- phase 1: xp[m][n] = sum_k x[m][k]*Wx[n][k] + b[n] ----------
__launch_bounds__(256)
__global__ void gemm_xp(const float* __restrict__ x,
                        const __half* __restrict__ Wx,
                        const float* __restrict__ bias,
                        float* __restrict__ xp) {
  __shared__ __align__(16) __half xs[32][256];

  const int bid = blockIdx.x;
  const int m0 = (bid >> 1) * 32;
  const int n0 = (bid & 1) * 256;
  const int tid = threadIdx.x;

  {
    int r = tid >> 3, cb = (tid & 7) * 32;
    const float* src = x + (size_t)(m0 + r) * NIN + cb;
    union { __half h[8]; uint4 u; } cv;
#pragma unroll
    for (int i = 0; i < 4; ++i) {
      float4 f0 = *(const float4*)(src + i * 8);
      float4 f1 = *(const float4*)(src + i * 8 + 4);
      cv.h[0] = __float2half(f0.x); cv.h[1] = __float2half(f0.y);
      cv.h[2] = __float2half(f0.z); cv.h[3] = __float2half(f0.w);
      cv.h[4] = __float2half(f1.x); cv.h[5] = __float2half(f1.y);
      cv.h[6] = __float2half(f1.z); cv.h[7] = __float2half(f1.w);
      *(uint4*)(void*)&xs[r][cb + i * 8] = cv.u;
    }
  }
  __syncthreads();

  const int rg = tid >> 6;
  const int c0 = tid & 63;

  float acc[8][4];
#pragma unroll
  for (int r = 0; r < 8; ++r)
#pragma unroll
    for (int j = 0; j < 4; ++j) acc[r][j] = 0.f;

  for (int kc = 0; kc < NIN; kc += 32) {
    uint4 w[4][4];
#pragma unroll
    for (int j = 0; j < 4; ++j) {
      const __half* wp = Wx + (size_t)(n0 + c0 + 64 * j) * NIN + kc;
#pragma unroll
      for (int i = 0; i < 4; ++i) w[j][i] = *(const uint4*)(wp + i * 8);
    }
#pragma unroll
    for (int r = 0; r < 8; ++r) {
      uint4 xv[4];
#pragma unroll
      for (int i = 0; i < 4; ++i)
        xv[i] = *(const uint4*)(const void*)&xs[rg * 8 + r][kc + i * 8];
#pragma unroll
      for (int j = 0; j < 4; ++j)
#pragma unroll
        for (int i = 0; i < 4; ++i) acc[r][j] = dot8(w[j][i], xv[i], acc[r][j]);
    }
  }

  float bj[4];
#pragma unroll
  for (int j = 0; j < 4; ++j) bj[j] = bias[n0 + c0 + 64 * j];
#pragma unroll
  for (int r = 0; r < 8; ++r) {
    float* dst = xp + (size_t)(m0 + rg * 8 + r) * HID + n0 + c0;
#pragma unroll
    for (int j = 0; j < 4; ++j) dst[64 * j] = acc[r][j] + bj[j];
  }
}

// ---------------- phase 2: sequential scan, one WG (512 thr) per batch -------
// Thread (rb = tid>>3, ks = tid&7) owns rows rb*8..rb*8+7, k in [ks*64,+64).
// ALL 8 rows register-resident (256 pinned u32, unified VGPR/AGPR file).
// h double-buffered in LDS at 72-half chunk stride (conflict-free).
// DPP butterfly (VALU) reduces the 8 ks partials; thread tid emits row tid.
// ONE barrier per step. xp_{t+1} prefetched. io block t+1 holds xp_t and is
// overwritten in place (same thread, read-before-write).
#define HCH 72   // h chunk stride in halves (144 B -> bank rot 4/chunk)
__launch_bounds__(512, 2)
__global__ void rnn_scan(const __half* __restrict__ Wh, float* io) {
  __shared__ __align__(16) __half hA[8 * HCH];      // h ping (1152 B)
  __shared__ __align__(16) __half hB[8 * HCH];      // h pong

  const int b   = blockIdx.x;
  const int tid = threadIdx.x;
  const int ks  = tid & 7;
  const int rb  = tid >> 3;
  const int R0  = rb * 8;
  const __half* wbase = Wh + (size_t)R0 * HID + ks * 64;

  // all 8 rows resident: 256 scalar u32, pinned against rematerialization
  uint32_t wres[8][32];
#pragma unroll
  for (int r = 0; r < 8; ++r)
#pragma unroll
    for (int i = 0; i < 8; ++i) {
      u32x4 q = *(const u32x4*)(const void*)(wbase + (size_t)r * HID + i * 8);
      wres[r][4 * i + 0] = q.x; wres[r][4 * i + 1] = q.y;
      wres[r][4 * i + 2] = q.z; wres[r][4 * i + 3] = q.w;
    }
#pragma unroll
  for (int r = 0; r < 8; ++r)
#pragma unroll
    for (int j = 0; j < 32; ++j)
      asm volatile("" : "+v"(wres[r][j]));

  // h0 = 0 (into hA); emit output block t=0
  const int hwb = (tid >> 6) * HCH + (tid & 63);
  hA[hwb] = __float2half(0.f);
  io[(size_t)b * HID + tid] = 0.f;
  __syncthreads();

  float* iorow = io + (size_t)BATCH * HID + (size_t)b * HID + tid;
  float xpv = *iorow;                    // xp_0

  auto do_step = [&](const __half* rd, __half* wr, float xpi, float* iop,
                     int t) -> float {
    // prefetch next step's xp — dots below hide the HBM latency
    float xpn = 0.f;
    if (t + 1 < T_STEPS) xpn = iop[BATCH * HID];

    float acc[8];
#pragma unroll
    for (int r = 0; r < 8; ++r) acc[r] = 0.f;

#pragma unroll
    for (int i = 0; i < 8; ++i) {
      u32x4 hj = *(const u32x4*)(const void*)((const char*)rd + ks * 144 + i * 16);
#pragma unroll
      for (int r = 0; r < 8; ++r) {
        acc[r] = fdot2u(wres[r][4 * i + 0], hj.x, acc[r]);
        acc[r] = fdot2u(wres[r][4 * i + 1], hj.y, acc[r]);
        acc[r] = fdot2u(wres[r][4 * i + 2], hj.z, acc[r]);
        acc[r] = fdot2u(wres[r][4 * i + 3], hj.w, acc[r]);
      }
    }

    // DPP butterfly over the 8 ks lanes (VALU pipe, no LDS traffic).
    // quad_perm(1,0,3,2)=0xB1 (^1), quad_perm(2,3,0,1)=0x4E (^2),
    // row_half_mirror=0x141 (valid ^4 stage: quad lanes equal by then).
    float s = 0.f;
#pragma unroll
    for (int r = 0; r < 8; ++r) {
      float v = acc[r];
      v = dppadd<0xB1>(v);
      v = dppadd<0x4E>(v);
      v = dppadd<0x141>(v);
      s = (ks == r) ? v : s;
    }

    s += xpi;                            // xp_t (prefetched)
    float e  = __expf(fminf(fmaxf(2.f * s, -40.f), 40.f));
    float hn = (e - 1.f) / (e + 1.f);
    *iop = hn;                           // h_{t+1} overwrites xp_t in place
    wr[hwb] = __float2half(hn);
    __syncthreads();
    return xpn;
  };

  for (int t = 0; t < T_STEPS; t += 2) {
    xpv = do_step(hA, hB, xpv, iorow, t);
    iorow += BATCH * HID;
    xpv = do_step(hB, hA, xpv, iorow, t + 1);
    iorow += BATCH * HID;
  }
}

extern "C" void kernel_launch(void* const* d_in, const int* in_sizes, int n_in,
                              void* d_out, int out_size, void* d_ws, size_t ws_size,
                              hipStream_t stream) {
  const float* x    = (const float*)d_in[0];   // (512,128,256) fp32
  const float* W    = (const float*)d_in[1];   // (512,768) fp32
  const float* bias = (const float*)d_in[2];   // (512,) fp32

  char* ws = (char*)d_ws;
  __half* Wx = (__half*)ws;                    // 512*256*2 = 256 KiB
  __half* Wh = (__half*)(ws + 262144);         // 512*512*2 = 512 KiB

  float* io = (float*)d_out;
  float* xp = io + (size_t)BATCH * HID;

  prep_w<<<1536, 256, 0, stream>>>(W, Wx, Wh);
  gemm_xp<<<4096, 256, 0, stream>>>(x, Wx, bias, xp);
  rnn_scan<<<BATCH, 512, 0, stream>>>(Wh, io);
}

// Round 11
// 1348.148 us; speedup vs baseline: 3.6065x; 3.6065x over previous
//
#include <hip/hip_runtime.h>
#include <hip/hip_bf16.h>
#include <hip/hip_fp16.h>
#include <stdint.h>

// Problem: T=512, B=128, INPUT=256, HIDDEN=512
//   xp = einsum('tbi,hi->tbh', x, Wx) + b      (phase 1, parallel GEMM)
//   h_{t+1} = tanh(xp_t + h_t @ Wh^T)          (phase 2, 512 sequential steps)
//   out = [h0(=0); h1..h512]  fp32, shape (513,128,512)
//
// R11 (resubmit; R10 round's bench = infra timeout, never measured).
// R11 = R10 with two fixes:
//  (BUG) hA init covered linear slots 0..511 of a 576-slot buffer; valid
//        h0 slots for k=456..511 (chunk 7, slots 8..63) stayed garbage ->
//        absmax 0.68. Fixed: per-thread slot (tid>>6)*HCH+(tid&63), the
//        exact 512 valid slots (R9's proven mapping).
//  (HARDEN) exchange protocol now write-through: em h-stores and partner
//        reads are RELAXED+AGENT atomics (sc1, serviced at the coherence
//        point -> no stale-L2 class at all); __syncthreads' vmcnt(0) drain
//        puts data at L3 before tid0 publishes the flag. No wbl2/inv.
// Structure (R10): TWO blocks per batch (grid 256 = full chip). Block owns
// 256 rows; thread (rb,ks) holds 4 rows x 64 k = 128 u32 f16 weights,
// genuinely VGPR-resident (128+~40 < 256 cap; waves_per_eu(2,2)).
// Per step the pair exchanges h-halves through d_out itself (the output
// write IS the exchange) with a per-pair flag handshake (flags in the t=0
// block, zeroed by prep_w, restored by zero_flags). Deadlock-safe:
// 256 blocks <= 256 CUs, all resident under any packing.
#define T_STEPS 512
#define BATCH   128
#define NIN     256
#define HID     512
#define BH      (BATCH * HID)

typedef _Float16 f16x2 __attribute__((ext_vector_type(2)));
typedef unsigned int u32x4 __attribute__((ext_vector_type(4)));

__device__ __forceinline__ float fdot2u(uint32_t a, uint32_t b, float c) {
#if __has_builtin(__builtin_amdgcn_fdot2)
  return __builtin_amdgcn_fdot2(__builtin_bit_cast(f16x2, a),
                                __builtin_bit_cast(f16x2, b), c, false);
#else
  __half2 ha = __builtin_bit_cast(__half2, a);
  __half2 hb = __builtin_bit_cast(__half2, b);
  return c + __half2float(ha.x) * __half2float(hb.x)
           + __half2float(ha.y) * __half2float(hb.y);
#endif
}

__device__ __forceinline__ float dot8(uint4 w, uint4 x, float a) {
  a = fdot2u(w.x, x.x, a);
  a = fdot2u(w.y, x.y, a);
  a = fdot2u(w.z, x.z, a);
  a = fdot2u(w.w, x.w, a);
  return a;
}

// v += (v shuffled by DPP ctrl) — VALU pipe (mov_dpp + add), no LDS traffic
template <int CTRL>
__device__ __forceinline__ float dppadd(float v) {
  int x = __builtin_bit_cast(int, v);
  int y = __builtin_amdgcn_update_dpp(x, x, CTRL, 0xF, 0xF, true);
  return v + __builtin_bit_cast(float, y);
}
// 8-lane-group sum: ^1, ^2 within quad, then row_half_mirror adds other quad
__device__ __forceinline__ float red8(float v) {
  v = dppadd<0xB1>(v);    // quad_perm(1,0,3,2)
  v = dppadd<0x4E>(v);    // quad_perm(2,3,0,1)
  v = dppadd<0x141>(v);   // row_half_mirror
  return v;
}

// ------ phase 0: split+convert W to f16; zero h0 block (incl. flag slots) ---
__global__ void prep_w(const float* __restrict__ W,
                       __half* __restrict__ Wx, __half* __restrict__ Wh,
                       float* __restrict__ io) {
  int idx = blockIdx.x * 256 + threadIdx.x;   // exactly 512*768 threads
  if (idx < BH) io[idx] = 0.f;                // h0 = 0 (also zeroes flags)
  int h = idx / (NIN + HID);
  int c = idx - h * (NIN + HID);
  float v = W[idx];
  if (c < NIN) Wx[h * NIN + c] = __float2half(v);
  else         Wh[h * HID + (c - NIN)] = __float2half(v);
}

// ---------------- phase 1: xp[m][n] = sum_k x[m][k]*Wx[n][k] + b[n] ----------
__launch_bounds__(256)
__global__ void gemm_xp(const float* __restrict__ x,
                        const __half* __restrict__ Wx,
                        const float* __restrict__ bias,
                        float* __restrict__ xp) {
  __shared__ __align__(16) __half xs[32][256];

  const int bid = blockIdx.x;
  const int m0 = (bid >> 1) * 32;
  const int n0 = (bid & 1) * 256;
  const int tid = threadIdx.x;

  {
    int r = tid >> 3, cb = (tid & 7) * 32;
    const float* src = x + (size_t)(m0 + r) * NIN + cb;
    union { __half h[8]; uint4 u; } cv;
#pragma unroll
    for (int i = 0; i < 4; ++i) {
      float4 f0 = *(const float4*)(src + i * 8);
      float4 f1 = *(const float4*)(src + i * 8 + 4);
      cv.h[0] = __float2half(f0.x); cv.h[1] = __float2half(f0.y);
      cv.h[2] = __float2half(f0.z); cv.h[3] = __float2half(f0.w);
      cv.h[4] = __float2half(f1.x); cv.h[5] = __float2half(f1.y);
      cv.h[6] = __float2half(f1.z); cv.h[7] = __float2half(f1.w);
      *(uint4*)(void*)&xs[r][cb + i * 8] = cv.u;
    }
  }
  __syncthreads();

  const int rg = tid >> 6;
  const int c0 = tid & 63;

  float acc[8][4];
#pragma unroll
  for (int r = 0; r < 8; ++r)
#pragma unroll
    for (int j = 0; j < 4; ++j) acc[r][j] = 0.f;

  for (int kc = 0; kc < NIN; kc += 32) {
    uint4 w[4][4];
#pragma unroll
    for (int j = 0; j < 4; ++j) {
      const __half* wp = Wx + (size_t)(n0 + c0 + 64 * j) * NIN + kc;
#pragma unroll
      for (int i = 0; i < 4; ++i) w[j][i] = *(const uint4*)(wp + i * 8);
    }
#pragma unroll
    for (int r = 0; r < 8; ++r) {
      uint4 xv[4];
#pragma unroll
      for (int i = 0; i < 4; ++i)
        xv[i] = *(const uint4*)(const void*)&xs[rg * 8 + r][kc + i * 8];
#pragma unroll
      for (int j = 0; j < 4; ++j)
#pragma unroll
        for (int i = 0; i < 4; ++i) acc[r][j] = dot8(w[j][i], xv[i], acc[r][j]);
    }
  }

  float bj[4];
#pragma unroll
  for (int j = 0; j < 4; ++j) bj[j] = bias[n0 + c0 + 64 * j];
#pragma unroll
  for (int r = 0; r < 8; ++r) {
    float* dst = xp + (size_t)(m0 + rg * 8 + r) * HID + n0 + c0;
#pragma unroll
    for (int j = 0; j < 4; ++j) dst[64 * j] = acc[r][j] + bj[j];
  }
}

// -------- phase 2: scan, TWO WGs per batch (grid 256, full chip) ------------
// Block (b = bid>>1, half = bid&1) owns rows [half*256, +256).
// Thread (rb = tid>>3, ks = tid&7): 4 rows x 64 k = 128 resident u32.
// h (512 f16) double-buffered in LDS (72-half chunk stride, conflict-free).
// DPP reduce over 8 ks lanes; lanes ks<4 emit row rb*4+ks.
#define HCH 72
__global__ __launch_bounds__(512)
__attribute__((amdgpu_waves_per_eu(2, 2)))
void rnn_scan(const __half* __restrict__ Wh, float* io) {
  __shared__ __align__(16) __half hA[8 * HCH];
  __shared__ __align__(16) __half hB[8 * HCH];

  const int bid  = blockIdx.x;
  const int b    = bid >> 1;
  const int half = bid & 1;
  const int ph0  = (1 - half) * 256;      // partner's k-range start
  const int tid  = threadIdx.x;
  const int ks   = tid & 7;
  const int rb   = tid >> 3;
  const bool em  = (ks < 4);              // emitter lanes

  // ---- weights: 4 rows x 64 k = 128 u32, loaded once, pinned ----
  uint32_t w[4][32];
  {
    const __half* wrow = Wh + (size_t)(half * 256 + rb * 4) * HID + ks * 64;
#pragma unroll
    for (int r = 0; r < 4; ++r)
#pragma unroll
      for (int i = 0; i < 8; ++i) {
        u32x4 q = *(const u32x4*)(const void*)(wrow + (size_t)r * HID + i * 8);
        w[r][4 * i + 0] = q.x; w[r][4 * i + 1] = q.y;
        w[r][4 * i + 2] = q.z; w[r][4 * i + 3] = q.w;
      }
  }
#pragma unroll
  for (int r = 0; r < 4; ++r)
#pragma unroll
    for (int j = 0; j < 32; ++j)
      asm volatile("" : "+v"(w[r][j]));

  // ---- addressing ----
  const int myrow = half * 256 + rb * 4 + ks;                 // em lanes
  float* iorow = io + (size_t)BH + (size_t)b * HID + myrow;   // io[1][b][row]
  const int hwaddr = (myrow >> 6) * HCH + (myrow & 63);       // my h LDS slot
  const int k0 = ph0 + 2 * (tid & 127);                       // partner fill
  const int poffw = ((k0 >> 6) * HCH + (k0 & 63)) >> 1;       // u32 LDS slot
  const float* pex = io + (size_t)BH + (size_t)b * HID + k0;  // io[1][b][k0]
  int* flagme = (int*)(io + (size_t)b * HID + half * 256);
  int* flagpt = (int*)(io + (size_t)b * HID + ph0);

  // ---- h0 = 0: R9's slot mapping covers EXACTLY the 512 valid slots ----
  hA[(tid >> 6) * HCH + (tid & 63)] = __float2half(0.f);
  __syncthreads();

  float xpv = em ? *iorow : 0.f;          // xp_0

  auto do_step = [&](const __half* rd, __half* wrb, float xpi, int t) -> float {
    float xpn = 0.f;
    if (em && t + 1 < T_STEPS) xpn = iorow[BH];

    float a0 = 0.f, a1 = 0.f, a2 = 0.f, a3 = 0.f;
    const char* rdp = (const char*)rd + ks * (HCH * 2);
#pragma unroll
    for (int i = 0; i < 8; ++i) {
      u32x4 hj = *(const u32x4*)(const void*)(rdp + i * 16);
      a0 = fdot2u(w[0][4*i+0], hj.x, a0); a0 = fdot2u(w[0][4*i+1], hj.y, a0);
      a0 = fdot2u(w[0][4*i+2], hj.z, a0); a0 = fdot2u(w[0][4*i+3], hj.w, a0);
      a1 = fdot2u(w[1][4*i+0], hj.x, a1); a1 = fdot2u(w[1][4*i+1], hj.y, a1);
      a1 = fdot2u(w[1][4*i+2], hj.z, a1); a1 = fdot2u(w[1][4*i+3], hj.w, a1);
      a2 = fdot2u(w[2][4*i+0], hj.x, a2); a2 = fdot2u(w[2][4*i+1], hj.y, a2);
      a2 = fdot2u(w[2][4*i+2], hj.z, a2); a2 = fdot2u(w[2][4*i+3], hj.w, a2);
      a3 = fdot2u(w[3][4*i+0], hj.x, a3); a3 = fdot2u(w[3][4*i+1], hj.y, a3);
      a3 = fdot2u(w[3][4*i+2], hj.z, a3); a3 = fdot2u(w[3][4*i+3], hj.w, a3);
    }
    a0 = red8(a0); a1 = red8(a1); a2 = red8(a2); a3 = red8(a3);
    float s = (ks == 0) ? a0 : (ks == 1) ? a1 : (ks == 2) ? a2 : a3;

    s += xpi;
    float e  = __expf(fminf(fmaxf(2.f * s, -40.f), 40.f));
    float hn = (e - 1.f) / (e + 1.f);
    if (em) {
      // write-through to coherence point (sc1): partner reads it from L3
      __hip_atomic_store(iorow, hn, __ATOMIC_RELAXED,
                         __HIP_MEMORY_SCOPE_AGENT);
      wrb[hwaddr] = __float2half(hn);     // my half into next h buffer
    }
    __syncthreads();                      // vmcnt(0) drain: h at L3

    if (t + 1 < T_STEPS) {
      if (tid == 0) {
        __hip_atomic_store(flagme, t + 1, __ATOMIC_RELAXED,
                           __HIP_MEMORY_SCOPE_AGENT);
        while (__hip_atomic_load(flagpt, __ATOMIC_RELAXED,
                                 __HIP_MEMORY_SCOPE_AGENT) < t + 1) {}
      }
      __syncthreads();
      asm volatile("" ::: "memory");
      if (tid < 128) {
        // agent-scope loads (sc1): serviced at L3, immune to stale L1/L2
        float f0 = __hip_atomic_load(pex, __ATOMIC_RELAXED,
                                     __HIP_MEMORY_SCOPE_AGENT);
        float f1 = __hip_atomic_load(pex + 1, __ATOMIC_RELAXED,
                                     __HIP_MEMORY_SCOPE_AGENT);
        uint32_t pk =
            (uint32_t)__builtin_bit_cast(unsigned short, __float2half(f0)) |
            ((uint32_t)__builtin_bit_cast(unsigned short, __float2half(f1))
             << 16);
        ((uint32_t*)wrb)[poffw] = pk;     // partner half into next h buffer
      }
      __syncthreads();
    }
    return xpn;
  };

  for (int t = 0; t < T_STEPS; t += 2) {
    xpv = do_step(hA, hB, xpv, t);
    iorow += BH; pex += BH;
    xpv = do_step(hB, hA, xpv, t + 1);
    iorow += BH; pex += BH;
  }
}

// -------- phase 3: restore flag slots of h0 to 0.0f --------------------------
__global__ void zero_flags(float* io) {
  int i = threadIdx.x;                    // 256 threads
  int b = i >> 1, half = i & 1;
  io[(size_t)b * HID + half * 256] = 0.f;
}

extern "C" void kernel_launch(void* const* d_in, const int* in_sizes, int n_in,
                              void* d_out, int out_size, void* d_ws, size_t ws_size,
                              hipStream_t stream) {
  const float* x    = (const float*)d_in[0];   // (512,128,256) fp32
  const float* W    = (const float*)d_in[1];   // (512,768) fp32
  const float* bias = (const float*)d_in[2];   // (512,) fp32

  char* ws = (char*)d_ws;
  __half* Wx = (__half*)ws;                    // 512*256*2 = 256 KiB
  __half* Wh = (__half*)(ws + 262144);         // 512*512*2 = 512 KiB

  float* io = (float*)d_out;
  float* xp = io + (size_t)BH;

  prep_w<<<1536, 256, 0, stream>>>(W, Wx, Wh, io);
  gemm_xp<<<4096, 256, 0, stream>>>(x, Wx, bias, xp);
  rnn_scan<<<256, 512, 0, stream>>>(Wh, io);
  zero_flags<<<1, 256, 0, stream>>>(io);
}

// Round 14
// 1162.377 us; speedup vs baseline: 4.1829x; 1.1598x over previous
//
#include <hip/hip_runtime.h>
#include <hip/hip_bf16.h>
#include <hip/hip_fp16.h>
#include <stdint.h>

// Problem: T=512, B=128, INPUT=256, HIDDEN=512
//   xp = einsum('tbi,hi->tbh', x, Wx) + b      (phase 1, parallel GEMM)
//   h_{t+1} = tanh(xp_t + h_t @ Wh^T)          (phase 2, 512 sequential steps)
//   out = [h0(=0); h1..h512]  fp32, shape (513,128,512)
//
// R12 (full resubmit; prior two rounds lost to a harness block-extraction
// mishap and a broker timeout): R11 measured 984us scan, latency-bound on
// the exchange (VALUBusy 31%, HBM 3.6%, no spill; cost = 2 L3 round-trips
// + vmcnt drain per step in the flag handshake).
// Fix: TAGGED-WORD exchange — one u32 packs (t+1)<<16 | h_f16; the data
// word IS the flag (self-validating), so the partner polls it directly:
// ONE L3 visibility latency per step, no drain, no flag protocol.
// Slot safety: 2 fixed parity slots; data-dependency bounds pair skew to
// <=1 step so a slot is never overwritten while readable.
//   slot0 = h0 output block (zeroed by prep_w, restored by zero_h0 after)
//   slot1 = Wx region of d_ws (dead after gemm; cleared by clear_slot1)
// Structure unchanged from R11 (proven): 2 blocks/batch (grid 256 = full
// chip), 128 weight u32/thread resident in unified VGPR/AGPR file
// (VGPR=88, no spill), h double-buffered in LDS (72-half chunk stride),
// DPP reduce, 1 barrier/step.
#define T_STEPS 512
#define BATCH   128
#define NIN     256
#define HID     512
#define BH      (BATCH * HID)

typedef _Float16 f16x2 __attribute__((ext_vector_type(2)));
typedef unsigned int u32x4 __attribute__((ext_vector_type(4)));

__device__ __forceinline__ float fdot2u(uint32_t a, uint32_t b, float c) {
#if __has_builtin(__builtin_amdgcn_fdot2)
  return __builtin_amdgcn_fdot2(__builtin_bit_cast(f16x2, a),
                                __builtin_bit_cast(f16x2, b), c, false);
#else
  __half2 ha = __builtin_bit_cast(__half2, a);
  __half2 hb = __builtin_bit_cast(__half2, b);
  return c + __half2float(ha.x) * __half2float(hb.x)
           + __half2float(ha.y) * __half2float(hb.y);
#endif
}

__device__ __forceinline__ float dot8(uint4 w, uint4 x, float a) {
  a = fdot2u(w.x, x.x, a);
  a = fdot2u(w.y, x.y, a);
  a = fdot2u(w.z, x.z, a);
  a = fdot2u(w.w, x.w, a);
  return a;
}

// v += (v shuffled by DPP ctrl) — VALU pipe (mov_dpp + add), no LDS traffic
template <int CTRL>
__device__ __forceinline__ float dppadd(float v) {
  int x = __builtin_bit_cast(int, v);
  int y = __builtin_amdgcn_update_dpp(x, x, CTRL, 0xF, 0xF, true);
  return v + __builtin_bit_cast(float, y);
}
// 8-lane-group sum: ^1, ^2 within quad, then row_half_mirror adds other quad
__device__ __forceinline__ float red8(float v) {
  v = dppadd<0xB1>(v);    // quad_perm(1,0,3,2)
  v = dppadd<0x4E>(v);    // quad_perm(2,3,0,1)
  v = dppadd<0x141>(v);   // row_half_mirror
  return v;
}

// ------ phase 0: split+convert W to f16; zero h0 block (= exchange slot0) ---
__global__ void prep_w(const float* __restrict__ W,
                       __half* __restrict__ Wx, __half* __restrict__ Wh,
                       float* __restrict__ io) {
  int idx = blockIdx.x * 256 + threadIdx.x;   // exactly 512*768 threads
  if (idx < BH) io[idx] = 0.f;                // h0 = 0 (slot0 tags = 0)
  int h = idx / (NIN + HID);
  int c = idx - h * (NIN + HID);
  float v = W[idx];
  if (c < NIN) Wx[h * NIN + c] = __float2half(v);
  else         Wh[h * HID + (c - NIN)] = __float2half(v);
}

// ---------------- phase 1: xp[m][n] = sum_k x[m][k]*Wx[n][k] + b[n] ----------
__launch_bounds__(256)
__global__ void gemm_xp(const float* __restrict__ x,
                        const __half* __restrict__ Wx,
                        const float* __restrict__ bias,
                        float* __restrict__ xp) {
  __shared__ __align__(16) __half xs[32][256];

  const int bid = blockIdx.x;
  const int m0 = (bid >> 1) * 32;
  const int n0 = (bid & 1) * 256;
  const int tid = threadIdx.x;

  {
    int r = tid >> 3, cb = (tid & 7) * 32;
    const float* src = x + (size_t)(m0 + r) * NIN + cb;
    union { __half h[8]; uint4 u; } cv;
#pragma unroll
    for (int i = 0; i < 4; ++i) {
      float4 f0 = *(const float4*)(src + i * 8);
      float4 f1 = *(const float4*)(src + i * 8 + 4);
      cv.h[0] = __float2half(f0.x); cv.h[1] = __float2half(f0.y);
      cv.h[2] = __float2half(f0.z); cv.h[3] = __float2half(f0.w);
      cv.h[4] = __float2half(f1.x); cv.h[5] = __float2half(f1.y);
      cv.h[6] = __float2half(f1.z); cv.h[7] = __float2half(f1.w);
      *(uint4*)(void*)&xs[r][cb + i * 8] = cv.u;
    }
  }
  __syncthreads();

  const int rg = tid >> 6;
  const int c0 = tid & 63;

  float acc[8][4];
#pragma unroll
  for (int r = 0; r < 8; ++r)
#pragma unroll
    for (int j = 0; j < 4; ++j) acc[r][j] = 0.f;

  for (int kc = 0; kc < NIN; kc += 32) {
    uint4 w[4][4];
#pragma unroll
    for (int j = 0; j < 4; ++j) {
      const __half* wp = Wx + (size_t)(n0 + c0 + 64 * j) * NIN + kc;
#pragma unroll
      for (int i = 0; i < 4; ++i) w[j][i] = *(const uint4*)(wp + i * 8);
    }
#pragma unroll
    for (int r = 0; r < 8; ++r) {
      uint4 xv[4];
#pragma unroll
      for (int i = 0; i < 4; ++i)
        xv[i] = *(const uint4*)(const void*)&xs[rg * 8 + r][kc + i * 8];
#pragma unroll
      for (int j = 0; j < 4; ++j)
#pragma unroll
        for (int i = 0; i < 4; ++i) acc[r][j] = dot8(w[j][i], xv[i], acc[r][j]);
    }
  }

  float bj[4];
#pragma unroll
  for (int j = 0; j < 4; ++j) bj[j] = bias[n0 + c0 + 64 * j];
#pragma unroll
  for (int r = 0; r < 8; ++r) {
    float* dst = xp + (size_t)(m0 + rg * 8 + r) * HID + n0 + c0;
#pragma unroll
    for (int j = 0; j < 4; ++j) dst[64 * j] = acc[r][j] + bj[j];
  }
}

// ---- clear exchange slot1 (dead Wx region) so stale bits can't alias tags --
__global__ void clear_slot1(uint32_t* ex1) {
  ex1[blockIdx.x * 256 + threadIdx.x] = 0u;   // 65536 words
}

// -------- phase 2: scan, TWO WGs per batch (grid 256, full chip) ------------
// Block (b = bid>>1, half = bid&1) owns rows [half*256, +256).
// Thread (rb = tid>>3, ks = tid&7): 4 rows x 64 k = 128 resident u32.
// h (512 f16) double-buffered in LDS (72-half chunk stride, conflict-free).
// DPP reduce over 8 ks lanes; lanes ks<4 emit row rb*4+ks.
// Exchange: tagged words (t+1)<<16|h_f16 in fixed slot[(t+1)&1]; reader
// polls the word itself (one L3 latency, no flag, no drain).
#define HCH 72
__global__ __launch_bounds__(512)
__attribute__((amdgpu_waves_per_eu(2, 2)))
void rnn_scan(const __half* __restrict__ Wh, float* io, uint32_t* ex1) {
  __shared__ __align__(16) __half hA[8 * HCH];
  __shared__ __align__(16) __half hB[8 * HCH];

  const int bid  = blockIdx.x;
  const int b    = bid >> 1;
  const int half = bid & 1;
  const int ph0  = (1 - half) * 256;      // partner's row-range start
  const int tid  = threadIdx.x;
  const int ks   = tid & 7;
  const int rb   = tid >> 3;
  const bool em  = (ks < 4);              // emitter lanes

  // ---- weights: 4 rows x 64 k = 128 u32, loaded once, pinned ----
  uint32_t w[4][32];
  {
    const __half* wrow = Wh + (size_t)(half * 256 + rb * 4) * HID + ks * 64;
#pragma unroll
    for (int r = 0; r < 4; ++r)
#pragma unroll
      for (int i = 0; i < 8; ++i) {
        u32x4 q = *(const u32x4*)(const void*)(wrow + (size_t)r * HID + i * 8);
        w[r][4 * i + 0] = q.x; w[r][4 * i + 1] = q.y;
        w[r][4 * i + 2] = q.z; w[r][4 * i + 3] = q.w;
      }
  }
#pragma unroll
  for (int r = 0; r < 4; ++r)
#pragma unroll
    for (int j = 0; j < 32; ++j)
      asm volatile("" : "+v"(w[r][j]));

  // ---- addressing ----
  const int myrow = half * 256 + rb * 4 + ks;                 // em lanes
  float* iorow = io + (size_t)BH + (size_t)b * HID + myrow;   // io[1][b][row]
  const int hwaddr = (myrow >> 6) * HCH + (myrow & 63);       // my h LDS slot
  // exchange bases: slot0 = io[0] block, slot1 = ex1 (Wx region)
  uint32_t* exw0 = (uint32_t*)io + (size_t)b * HID + myrow;   // em writes
  uint32_t* exw1 = ex1 + (size_t)b * HID + myrow;
  const uint32_t* exr0 = (uint32_t*)io + (size_t)b * HID + ph0 + tid;
  const uint32_t* exr1 = ex1 + (size_t)b * HID + ph0 + tid;   // tid<256 reads
  const int kg = ph0 + tid;                                   // partner h idx
  const int paddr = (kg >> 6) * HCH + (kg & 63);

  // ---- h0 = 0: the 512 valid slots exactly ----
  hA[(tid >> 6) * HCH + (tid & 63)] = __float2half(0.f);
  __syncthreads();

  float xpv = em ? *iorow : 0.f;          // xp_0

  auto do_step = [&](const __half* rd, __half* wrb, uint32_t* exw,
                     const uint32_t* exr, float xpi, int t) -> float {
    float xpn = 0.f;
    if (em && t + 1 < T_STEPS) xpn = iorow[BH];

    float a0 = 0.f, a1 = 0.f, a2 = 0.f, a3 = 0.f;
    const char* rdp = (const char*)rd + ks * (HCH * 2);
#pragma unroll
    for (int i = 0; i < 8; ++i) {
      u32x4 hj = *(const u32x4*)(const void*)(rdp + i * 16);
      a0 = fdot2u(w[0][4*i+0], hj.x, a0); a0 = fdot2u(w[0][4*i+1], hj.y, a0);
      a0 = fdot2u(w[0][4*i+2], hj.z, a0); a0 = fdot2u(w[0][4*i+3], hj.w, a0);
      a1 = fdot2u(w[1][4*i+0], hj.x, a1); a1 = fdot2u(w[1][4*i+1], hj.y, a1);
      a1 = fdot2u(w[1][4*i+2], hj.z, a1); a1 = fdot2u(w[1][4*i+3], hj.w, a1);
      a2 = fdot2u(w[2][4*i+0], hj.x, a2); a2 = fdot2u(w[2][4*i+1], hj.y, a2);
      a2 = fdot2u(w[2][4*i+2], hj.z, a2); a2 = fdot2u(w[2][4*i+3], hj.w, a2);
      a3 = fdot2u(w[3][4*i+0], hj.x, a3); a3 = fdot2u(w[3][4*i+1], hj.y, a3);
      a3 = fdot2u(w[3][4*i+2], hj.z, a3); a3 = fdot2u(w[3][4*i+3], hj.w, a3);
    }
    a0 = red8(a0); a1 = red8(a1); a2 = red8(a2); a3 = red8(a3);
    float s = (ks == 0) ? a0 : (ks == 1) ? a1 : (ks == 2) ? a2 : a3;

    s += xpi;
    float e  = __expf(fminf(fmaxf(2.f * s, -40.f), 40.f));
    float hn = (e - 1.f) / (e + 1.f);

    const unsigned short hf16 =
        __builtin_bit_cast(unsigned short, __float2half(hn));
    if (em) {
      *iorow = hn;                        // output (plain store, in-place)
      wrb[hwaddr] = __builtin_bit_cast(__half, hf16);  // own half -> LDS
    }

    if (t + 1 < T_STEPS) {
      if (em) {
        uint32_t word = ((uint32_t)(t + 1) << 16) | (uint32_t)hf16;
        __hip_atomic_store(exw, word, __ATOMIC_RELAXED,
                           __HIP_MEMORY_SCOPE_AGENT);
      }
      asm volatile("" ::: "memory");      // store must not sink below poll
      if (tid < 256) {
        uint32_t wv;
        do {
          wv = __hip_atomic_load(exr, __ATOMIC_RELAXED,
                                 __HIP_MEMORY_SCOPE_AGENT);
        } while ((wv >> 16) != (uint32_t)(t + 1));
        wrb[paddr] = __builtin_bit_cast(__half, (unsigned short)(wv & 0xFFFF));
      }
    }
    __syncthreads();
    return xpn;
  };

  for (int t = 0; t < T_STEPS; t += 2) {
    xpv = do_step(hA, hB, exw1, exr1, xpv, t);      // writes slot parity 1
    iorow += BH;
    xpv = do_step(hB, hA, exw0, exr0, xpv, t + 1);  // writes slot parity 0
    iorow += BH;
  }
}

// -------- phase 3: restore the whole h0 block to 0.0f ------------------------
__global__ void zero_h0(float* io) {
  io[blockIdx.x * 256 + threadIdx.x] = 0.f;   // 65536 floats
}

extern "C" void kernel_launch(void* const* d_in, const int* in_sizes, int n_in,
                              void* d_out, int out_size, void* d_ws, size_t ws_size,
                              hipStream_t stream) {
  const float* x    = (const float*)d_in[0];   // (512,128,256) fp32
  const float* W    = (const float*)d_in[1];   // (512,768) fp32
  const float* bias = (const float*)d_in[2];   // (512,) fp32

  char* ws = (char*)d_ws;
  __half* Wx = (__half*)ws;                    // 512*256*2 = 256 KiB
  __half* Wh = (__half*)(ws + 262144);         // 512*512*2 = 512 KiB

  float* io = (float*)d_out;
  float* xp = io + (size_t)BH;

  prep_w<<<1536, 256, 0, stream>>>(W, Wx, Wh, io);
  gemm_xp<<<4096, 256, 0, stream>>>(x, Wx, bias, xp);
  clear_slot1<<<256, 256, 0, stream>>>((uint32_t*)ws);   // Wx dead after gemm
  rnn_scan<<<256, 512, 0, stream>>>(Wh, io, (uint32_t*)ws);
  zero_h0<<<256, 256, 0, stream>>>(io);
}